// Round 5
// baseline (334.053 us; speedup 1.0000x reference)
//
#include <hip/hip_runtime.h>

// dims from the reference
#define BB 2
#define PP 512
#define NN 8
#define HH 32

typedef float f4     __attribute__((ext_vector_type(4)));
typedef float f32x4  __attribute__((ext_vector_type(4)));
typedef short bf16x8 __attribute__((ext_vector_type(8)));

// float -> bf16 bits, round-nearest-even
__device__ __forceinline__ short f2bf(float f) {
  union { float f; unsigned u; } v; v.f = f;
  unsigned r = v.u + 0x7FFFu + ((v.u >> 16) & 1u);
  return (short)(r >> 16);
}

// ---------------------------------------------------------------------------
// Kernel 0 (aux): blocks 0..255  : WT[n][h1][h3][h2] = W[n][h1][h2][h3]
//                 blocks 256..383: eB = bf16(e)
// ---------------------------------------------------------------------------
__global__ __launch_bounds__(256) void aux_kernel(
    const float* __restrict__ W, const float* __restrict__ e,
    float* __restrict__ WT, short* __restrict__ eB) {
  const int bid = blockIdx.x;
  const int t   = threadIdx.x;

  if (bid < 256) {                     // ---- W transpose (32x32 per block) ----
    __shared__ float ls[32][33];
    const float* src = W  + (size_t)bid * 1024;
    float*       dst = WT + (size_t)bid * 1024;
    #pragma unroll
    for (int r = 0; r < 4; ++r) {
      const int h2 = r * 8 + (t >> 5), h3 = t & 31;
      ls[h2][h3] = src[h2 * 32 + h3];
    }
    __syncthreads();
    #pragma unroll
    for (int r = 0; r < 4; ++r) {
      const int h3 = r * 8 + (t >> 5), h2 = t & 31;
      dst[h3 * 32 + h2] = ls[h2][h3];
    }
  } else {                             // ---- e -> bf16 ----
    const int i = ((bid - 256) * 256 + t) * 8;
    const f4 e0 = *(const f4*)(e + i);
    const f4 e1 = *(const f4*)(e + i + 4);
    bf16x8 v;
    v[0] = f2bf(e0[0]); v[1] = f2bf(e0[1]); v[2] = f2bf(e0[2]); v[3] = f2bf(e0[3]);
    v[4] = f2bf(e1[0]); v[5] = f2bf(e1[1]); v[6] = f2bf(e1[2]); v[7] = f2bf(e1[3]);
    *(bf16x8*)(eB + i) = v;
  }
}

// ---------------------------------------------------------------------------
// Kernel 1: vmain v5 — fully fused. Per block (b,p1):
//   phase 1: tmp[n][h3][h2] = bf16( sum_h1 d[b,p1,n,h1] * WT[n][h1][h3][h2] )
//            computed in-LDS (16 KB, aliases the transpose buffer).
//   phase 2: load MFMA A-fragments (bfr) from LDS, barrier.
//   phase 3: per p2-tile: MFMA vs eB, per-wave LDS transpose (swizzled),
//            1KB-dense global_store_dwordx4. Plain cached stores (NT hurt).
// ---------------------------------------------------------------------------
__global__ __launch_bounds__(256, 4) void vmain_kernel(
    const float* __restrict__ d, const float* __restrict__ WT,
    const short* __restrict__ eB, float* __restrict__ out) {
  const int bid = blockIdx.x;
  const int b   = bid >> 9;
  const int p1  = bid & 511;
  const int t   = threadIdx.x;
  const int wv  = t >> 6;
  const int l   = t & 63;
  const int lr  = l & 15;
  const int lk  = l >> 4;

  __shared__ float lbuf[4][16][128];   // 32 KB; first 16 KB aliases tsh
  __shared__ float dsh[NN * HH];       // 1 KB: d[b,p1,:,:]
  short* tsh = (short*)&lbuf[0][0][0]; // [n][h3][h2] bf16, 8*32*32*2 = 16 KB

  dsh[t] = d[(size_t)(b * PP + p1) * (NN * HH) + t];
  __syncthreads();

  // ---- phase 1: tmp into tsh. thread = (n = t>>5, h3 = t&31) ----
  {
    const int n_p = t >> 5, h3_p = t & 31;
    float acc[32];
    #pragma unroll
    for (int q = 0; q < 32; ++q) acc[q] = 0.f;
    const float* wtb = WT + (size_t)n_p * 32768 + h3_p * 32;
    for (int h1 = 0; h1 < 32; ++h1) {
      const float dval = dsh[n_p * 32 + h1];
      const float* wrow = wtb + (size_t)h1 * 1024;
      #pragma unroll
      for (int g = 0; g < 8; ++g) {
        const f4 w = *(const f4*)(wrow + g * 4);
        acc[g * 4 + 0] = fmaf(dval, w[0], acc[g * 4 + 0]);
        acc[g * 4 + 1] = fmaf(dval, w[1], acc[g * 4 + 1]);
        acc[g * 4 + 2] = fmaf(dval, w[2], acc[g * 4 + 2]);
        acc[g * 4 + 3] = fmaf(dval, w[3], acc[g * 4 + 3]);
      }
    }
    #pragma unroll
    for (int g = 0; g < 4; ++g) {
      bf16x8 v;
      #pragma unroll
      for (int q = 0; q < 8; ++q) v[q] = f2bf(acc[g * 8 + q]);
      *(bf16x8*)(tsh + n_p * 1024 + h3_p * 32 + g * 8) = v;
    }
  }
  __syncthreads();

  // ---- phase 2: A-fragments from tsh: rows h3 = c*16+lr, k = h2 = 8*lk+j ----
  bf16x8 bfr[8][2];
  #pragma unroll
  for (int n = 0; n < 8; ++n)
    #pragma unroll
    for (int c = 0; c < 2; ++c)
      bfr[n][c] = *(const bf16x8*)(tsh + n * 1024 + (c * 16 + lr) * 32 + lk * 8);
  __syncthreads();                     // tsh dead; lbuf reuse is now safe

  // ---- phase 3: MFMA + per-wave LDS transpose + dense stores ----
  float* wl = &lbuf[wv][0][0];
  const short* ebb  = eB + (size_t)b * (PP * NN * HH);
  float*       outb = out + (size_t)(b * PP + p1) * (PP * NN * HH);
  const f32x4  z    = {0.f, 0.f, 0.f, 0.f};

  for (int i = 0; i < 8; ++i) {
    const int m0 = (wv * 8 + i) * 16;  // p2 tile base
    #pragma unroll
    for (int half = 0; half < 2; ++half) {
      const int n0 = half * 4;
      #pragma unroll
      for (int nn = 0; nn < 4; ++nn) {
        const int n = n0 + nn;
        const bf16x8 a =
            *(const bf16x8*)(ebb + (size_t)((m0 + lr) * NN + n) * HH + lk * 8);
        const f32x4 c0 = __builtin_amdgcn_mfma_f32_16x16x32_bf16(bfr[n][0], a, z, 0, 0, 0);
        const f32x4 c1 = __builtin_amdgcn_mfma_f32_16x16x32_bf16(bfr[n][1], a, z, 0, 0, 0);
        const int s0 = (nn * 8 + lk)     ^ (lr & 7);
        const int s1 = (nn * 8 + 4 + lk) ^ (lr & 7);
        *(f32x4*)(wl + lr * 128 + s0 * 4) = c0;
        *(f32x4*)(wl + lr * 128 + s1 * 4) = c1;
      }
      #pragma unroll
      for (int j = 0; j < 8; ++j) {
        const int row  = 2 * j + (l >> 5);
        const int slot = l & 31;
        const f32x4 v = *(const f32x4*)(wl + row * 128 + ((slot ^ (row & 7)) * 4));
        *(f32x4*)(outb + (size_t)(m0 + row) * (NN * HH) + n0 * HH + slot * 4) = v;
      }
    }
  }
}

// ---------------------------------------------------------------------------
// Fallback (no/small ws): self-contained fused kernel (correct, slower).
// ---------------------------------------------------------------------------
__global__ __launch_bounds__(256, 4) void fused_kernel(
    const float* __restrict__ d, const float* __restrict__ e,
    const float* __restrict__ W, float* __restrict__ out) {
  const int bid = blockIdx.x;
  const int b   = bid >> 9;
  const int p1  = bid & 511;
  const int t   = threadIdx.x;

  __shared__ float dsh[NN * HH];
  __shared__ short tsh[NN * HH * HH];
  dsh[t] = d[(size_t)(b * PP + p1) * (NN * HH) + t];
  __syncthreads();

  const int h3  = t & 31;
  const int h2b = t >> 5;
  for (int n = 0; n < 8; ++n) {
    f4 dv[8];
    #pragma unroll
    for (int j = 0; j < 8; ++j) dv[j] = *(const f4*)&dsh[n * 32 + j * 4];
    const float* Wn = W + (size_t)n * (HH * HH * HH);
    #pragma unroll
    for (int h2s = 0; h2s < 4; ++h2s) {
      const int h2 = h2s * 8 + h2b;
      float acc = 0.f;
      #pragma unroll
      for (int j = 0; j < 8; ++j)
        #pragma unroll
        for (int k = 0; k < 4; ++k)
          acc = fmaf(dv[j][k], Wn[(j * 4 + k) * 1024 + h2 * 32 + h3], acc);
      tsh[n * 1024 + h3 * 32 + h2] = f2bf(acc);
    }
  }
  __syncthreads();

  const int wv = t >> 6;
  const int l  = t & 63;
  const int lr = l & 15;
  const int lk = l >> 4;
  bf16x8 bfr[8][2];
  #pragma unroll
  for (int n = 0; n < 8; ++n)
    #pragma unroll
    for (int c = 0; c < 2; ++c)
      bfr[n][c] = *(const bf16x8*)&tsh[n * (HH * HH) + (c * 16 + lr) * 32 + lk * 8];

  const float* eb   = e + (size_t)b * (PP * NN * HH);
  float*       outb = out + (size_t)(b * PP + p1) * (PP * NN * HH);
  const f32x4  z    = {0.f, 0.f, 0.f, 0.f};
  for (int i = 0; i < 8; ++i) {
    const int m0 = (wv * 8 + i) * 16;
    #pragma unroll
    for (int n = 0; n < 8; ++n) {
      const float* ep = eb + (size_t)(((m0 + lr) * NN + n) * HH + lk * 8);
      const f4 e0 = *(const f4*)ep;
      const f4 e1 = *(const f4*)(ep + 4);
      bf16x8 a;
      a[0] = f2bf(e0[0]); a[1] = f2bf(e0[1]); a[2] = f2bf(e0[2]); a[3] = f2bf(e0[3]);
      a[4] = f2bf(e1[0]); a[5] = f2bf(e1[1]); a[6] = f2bf(e1[2]); a[7] = f2bf(e1[3]);
      const f32x4 c0 = __builtin_amdgcn_mfma_f32_16x16x32_bf16(bfr[n][0], a, z, 0, 0, 0);
      const f32x4 c1 = __builtin_amdgcn_mfma_f32_16x16x32_bf16(bfr[n][1], a, z, 0, 0, 0);
      float* op = outb + (size_t)(m0 + lr) * (NN * HH) + n * HH + lk * 4;
      *(f32x4*)op        = c0;
      *(f32x4*)(op + 16) = c1;
    }
  }
}

extern "C" void kernel_launch(void* const* d_in, const int* in_sizes, int n_in,
                              void* d_out, int out_size, void* d_ws, size_t ws_size,
                              hipStream_t stream) {
  const float* d = (const float*)d_in[0];
  const float* e = (const float*)d_in[1];
  const float* W = (const float*)d_in[2];
  float* out = (float*)d_out;

  const size_t wt_bytes = (size_t)NN * HH * HH * HH * sizeof(float);   // 1 MB
  const size_t eb_bytes = (size_t)BB * PP * NN * HH * sizeof(short);   // 512 KB
  if (ws_size >= wt_bytes + eb_bytes) {
    float* WT = (float*)d_ws;
    short* eB = (short*)((char*)d_ws + wt_bytes);
    aux_kernel<<<dim3(256 + 128), dim3(256), 0, stream>>>(W, e, WT, eB);
    vmain_kernel<<<dim3(BB * PP), dim3(256), 0, stream>>>(d, WT, eB, out);
  } else {
    fused_kernel<<<dim3(BB * PP), dim3(256), 0, stream>>>(d, e, W, out);
  }
}

// Round 6
// 133.223 us; speedup vs baseline: 2.5075x; 2.5075x over previous
//
#include <hip/hip_runtime.h>

// dims from the reference
#define BB 2
#define PP 512
#define NN 8
#define HH 32

typedef float f4     __attribute__((ext_vector_type(4)));
typedef float f32x4  __attribute__((ext_vector_type(4)));
typedef short bf16x8 __attribute__((ext_vector_type(8)));
typedef short bf16x4 __attribute__((ext_vector_type(4)));

// float -> bf16 bits, round-nearest-even
__device__ __forceinline__ short f2bf(float f) {
  union { float f; unsigned u; } v; v.f = f;
  unsigned r = v.u + 0x7FFFu + ((v.u >> 16) & 1u);
  return (short)(r >> 16);
}

// ---------------------------------------------------------------------------
// Kernel 0 (aux): blocks 0..255  : WT[n][h1][h3][h2] = W[n][h1][h2][h3]
//                 blocks 256..383: eB = bf16(e)
// ---------------------------------------------------------------------------
__global__ __launch_bounds__(256) void aux_kernel(
    const float* __restrict__ W, const float* __restrict__ e,
    float* __restrict__ WT, short* __restrict__ eB) {
  const int bid = blockIdx.x;
  const int t   = threadIdx.x;

  if (bid < 256) {                     // ---- W transpose (32x32 per block) ----
    __shared__ float ls[32][33];
    const float* src = W  + (size_t)bid * 1024;
    float*       dst = WT + (size_t)bid * 1024;
    #pragma unroll
    for (int r = 0; r < 4; ++r) {
      const int h2 = r * 8 + (t >> 5), h3 = t & 31;
      ls[h2][h3] = src[h2 * 32 + h3];
    }
    __syncthreads();
    #pragma unroll
    for (int r = 0; r < 4; ++r) {
      const int h3 = r * 8 + (t >> 5), h2 = t & 31;
      dst[h3 * 32 + h2] = ls[h2][h3];
    }
  } else {                             // ---- e -> bf16 ----
    const int i = ((bid - 256) * 256 + t) * 8;
    const f4 e0 = *(const f4*)(e + i);
    const f4 e1 = *(const f4*)(e + i + 4);
    bf16x8 v;
    v[0] = f2bf(e0[0]); v[1] = f2bf(e0[1]); v[2] = f2bf(e0[2]); v[3] = f2bf(e0[3]);
    v[4] = f2bf(e1[0]); v[5] = f2bf(e1[1]); v[6] = f2bf(e1[2]); v[7] = f2bf(e1[3]);
    *(bf16x8*)(eB + i) = v;
  }
}

// ---------------------------------------------------------------------------
// Kernel 1: vmain v6 — fused, coalesced, low register pressure.
//   phase 1: tmp[n][h3][h2] -> tsh (16 KB LDS). Thread = (h3 = t>>3,
//            h2 quad = t&7): each wave's WT load is 1 KB DENSE; 4 acc regs.
//   phase 3: per p2-tile, per 2-n quarter: reload 4 A-frags from tsh
//            (16 VGPRs live, no spills), 4 MFMA, XOR-swizzled per-wave LDS
//            transpose (lbuf 16 KB), 256B-segment-dense dwordx4 stores.
//   LDS total 33 KB -> 4 blocks/CU. tsh persists (no aliasing).
// ---------------------------------------------------------------------------
__global__ __launch_bounds__(256, 4) void vmain_kernel(
    const float* __restrict__ d, const float* __restrict__ WT,
    const short* __restrict__ eB, float* __restrict__ out) {
  const int bid = blockIdx.x;
  const int b   = bid >> 9;
  const int p1  = bid & 511;
  const int t   = threadIdx.x;
  const int wv  = t >> 6;
  const int l   = t & 63;
  const int lr  = l & 15;
  const int lk  = l >> 4;

  __shared__ float lbuf[4][16][64];    // 16 KB per-wave transpose buffers
  __shared__ short tsh[NN * HH * HH];  // 16 KB: tmp[n][h3][h2] bf16
  __shared__ float dsh[NN * HH];       // 1 KB: d[b,p1,:,:]

  dsh[t] = d[(size_t)(b * PP + p1) * (NN * HH) + t];
  __syncthreads();

  // ---- phase 1: thread = (h3p = t>>3, h2q = t&7); wave loads 1KB dense ----
  {
    const int h3p = t >> 3;            // 0..31
    const int h2q = t & 7;             // h2 base = h2q*4
    const float* wtb = WT + h3p * 32 + h2q * 4;
    #pragma unroll 1
    for (int n = 0; n < 8; ++n) {
      f4 acc = {0.f, 0.f, 0.f, 0.f};
      const float* wn = wtb + (size_t)n * 32768;
      #pragma unroll 8
      for (int h1 = 0; h1 < 32; ++h1) {
        const f4 w = *(const f4*)(wn + h1 * 1024);
        const float dv = dsh[n * 32 + h1];   // LDS broadcast
        acc[0] = fmaf(dv, w[0], acc[0]);
        acc[1] = fmaf(dv, w[1], acc[1]);
        acc[2] = fmaf(dv, w[2], acc[2]);
        acc[3] = fmaf(dv, w[3], acc[3]);
      }
      bf16x4 v;
      v[0] = f2bf(acc[0]); v[1] = f2bf(acc[1]);
      v[2] = f2bf(acc[2]); v[3] = f2bf(acc[3]);
      *(bf16x4*)(tsh + n * 1024 + h3p * 32 + h2q * 4) = v;
    }
  }
  __syncthreads();

  // ---- phase 3: MFMA (A-frags re-read from tsh) + swizzled LDS transpose ----
  float*       wl   = &lbuf[wv][0][0];  // [16][64]
  const short* ebb  = eB + (size_t)b * (PP * NN * HH);
  float*       outb = out + (size_t)(b * PP + p1) * (PP * NN * HH);
  const f32x4  z    = {0.f, 0.f, 0.f, 0.f};
  const int    sw   = lr & 7;

  for (int i = 0; i < 8; ++i) {
    const int m0 = (wv * 8 + i) * 16;  // p2 tile base
    #pragma unroll
    for (int q = 0; q < 4; ++q) {
      const int n0 = q * 2;
      // A-fragments from tsh (rows h3 = c*16+lr, k = h2 = lk*8..+7)
      const bf16x8 f00 = *(const bf16x8*)(tsh + (n0 + 0) * 1024 + lr * 32 + lk * 8);
      const bf16x8 f01 = *(const bf16x8*)(tsh + (n0 + 0) * 1024 + (16 + lr) * 32 + lk * 8);
      const bf16x8 f10 = *(const bf16x8*)(tsh + (n0 + 1) * 1024 + lr * 32 + lk * 8);
      const bf16x8 f11 = *(const bf16x8*)(tsh + (n0 + 1) * 1024 + (16 + lr) * 32 + lk * 8);
      // B-fragments from eB (p2 col = m0+lr, k = h2 = lk*8..+7)
      const bf16x8 a0 =
          *(const bf16x8*)(ebb + (size_t)((m0 + lr) * NN + n0) * HH + lk * 8);
      const bf16x8 a1 =
          *(const bf16x8*)(ebb + (size_t)((m0 + lr) * NN + n0 + 1) * HH + lk * 8);
      const f32x4 c00 = __builtin_amdgcn_mfma_f32_16x16x32_bf16(f00, a0, z, 0, 0, 0);
      const f32x4 c01 = __builtin_amdgcn_mfma_f32_16x16x32_bf16(f01, a0, z, 0, 0, 0);
      const f32x4 c10 = __builtin_amdgcn_mfma_f32_16x16x32_bf16(f10, a1, z, 0, 0, 0);
      const f32x4 c11 = __builtin_amdgcn_mfma_f32_16x16x32_bf16(f11, a1, z, 0, 0, 0);
      // swizzled write: logical slot s = nn*8 + c*4 + lk -> physical s^sw
      *(f32x4*)(wl + lr * 64 + ((lk)      ^ sw) * 4) = c00;
      *(f32x4*)(wl + lr * 64 + ((4 + lk)  ^ sw) * 4) = c01;
      *(f32x4*)(wl + lr * 64 + ((8 + lk)  ^ sw) * 4) = c10;
      *(f32x4*)(wl + lr * 64 + ((12 + lk) ^ sw) * 4) = c11;
      // transpose read + dense store (4 rows x 256B per instruction)
      #pragma unroll
      for (int j = 0; j < 4; ++j) {
        const int row  = 4 * j + lk;
        const int slot = lr;
        const f32x4 v =
            *(const f32x4*)(wl + row * 64 + ((slot ^ (row & 7)) * 4));
        *(f32x4*)(outb + (size_t)(m0 + row) * (NN * HH) + n0 * HH + slot * 4) = v;
      }
    }
  }
}

// ---------------------------------------------------------------------------
// Fallback (no/small ws): self-contained fused kernel (correct, slower).
// ---------------------------------------------------------------------------
__global__ __launch_bounds__(256, 4) void fused_kernel(
    const float* __restrict__ d, const float* __restrict__ e,
    const float* __restrict__ W, float* __restrict__ out) {
  const int bid = blockIdx.x;
  const int b   = bid >> 9;
  const int p1  = bid & 511;
  const int t   = threadIdx.x;

  __shared__ float dsh[NN * HH];
  __shared__ short tsh[NN * HH * HH];
  dsh[t] = d[(size_t)(b * PP + p1) * (NN * HH) + t];
  __syncthreads();

  const int h3  = t & 31;
  const int h2b = t >> 5;
  for (int n = 0; n < 8; ++n) {
    f4 dv[8];
    #pragma unroll
    for (int j = 0; j < 8; ++j) dv[j] = *(const f4*)&dsh[n * 32 + j * 4];
    const float* Wn = W + (size_t)n * (HH * HH * HH);
    #pragma unroll
    for (int h2s = 0; h2s < 4; ++h2s) {
      const int h2 = h2s * 8 + h2b;
      float acc = 0.f;
      #pragma unroll
      for (int j = 0; j < 8; ++j)
        #pragma unroll
        for (int k = 0; k < 4; ++k)
          acc = fmaf(dv[j][k], Wn[(j * 4 + k) * 1024 + h2 * 32 + h3], acc);
      tsh[n * 1024 + h3 * 32 + h2] = f2bf(acc);
    }
  }
  __syncthreads();

  const int wv = t >> 6;
  const int l  = t & 63;
  const int lr = l & 15;
  const int lk = l >> 4;
  bf16x8 bfr[8][2];
  #pragma unroll
  for (int n = 0; n < 8; ++n)
    #pragma unroll
    for (int c = 0; c < 2; ++c)
      bfr[n][c] = *(const bf16x8*)&tsh[n * (HH * HH) + (c * 16 + lr) * 32 + lk * 8];

  const float* eb   = e + (size_t)b * (PP * NN * HH);
  float*       outb = out + (size_t)(b * PP + p1) * (PP * NN * HH);
  const f32x4  z    = {0.f, 0.f, 0.f, 0.f};
  for (int i = 0; i < 8; ++i) {
    const int m0 = (wv * 8 + i) * 16;
    #pragma unroll
    for (int n = 0; n < 8; ++n) {
      const float* ep = eb + (size_t)(((m0 + lr) * NN + n) * HH + lk * 8);
      const f4 e0 = *(const f4*)ep;
      const f4 e1 = *(const f4*)(ep + 4);
      bf16x8 a;
      a[0] = f2bf(e0[0]); a[1] = f2bf(e0[1]); a[2] = f2bf(e0[2]); a[3] = f2bf(e0[3]);
      a[4] = f2bf(e1[0]); a[5] = f2bf(e1[1]); a[6] = f2bf(e1[2]); a[7] = f2bf(e1[3]);
      const f32x4 c0 = __builtin_amdgcn_mfma_f32_16x16x32_bf16(bfr[n][0], a, z, 0, 0, 0);
      const f32x4 c1 = __builtin_amdgcn_mfma_f32_16x16x32_bf16(bfr[n][1], a, z, 0, 0, 0);
      float* op = outb + (size_t)(m0 + lr) * (NN * HH) + n * HH + lk * 4;
      *(f32x4*)op        = c0;
      *(f32x4*)(op + 16) = c1;
    }
  }
}

extern "C" void kernel_launch(void* const* d_in, const int* in_sizes, int n_in,
                              void* d_out, int out_size, void* d_ws, size_t ws_size,
                              hipStream_t stream) {
  const float* d = (const float*)d_in[0];
  const float* e = (const float*)d_in[1];
  const float* W = (const float*)d_in[2];
  float* out = (float*)d_out;

  const size_t wt_bytes = (size_t)NN * HH * HH * HH * sizeof(float);   // 1 MB
  const size_t eb_bytes = (size_t)BB * PP * NN * HH * sizeof(short);   // 512 KB
  if (ws_size >= wt_bytes + eb_bytes) {
    float* WT = (float*)d_ws;
    short* eB = (short*)((char*)d_ws + wt_bytes);
    aux_kernel<<<dim3(256 + 128), dim3(256), 0, stream>>>(W, e, WT, eB);
    vmain_kernel<<<dim3(BB * PP), dim3(256), 0, stream>>>(d, WT, eB, out);
  } else {
    fused_kernel<<<dim3(BB * PP), dim3(256), 0, stream>>>(d, e, W, out);
  }
}